// Round 12
// baseline (697.653 us; speedup 1.0000x reference)
//
#include <hip/hip_runtime.h>

#define F 128
#define SEG 1024      // nodes per scan segment
#define TN 32         // nodes per GEMM tile
#define GRID 1024     // mega-kernel blocks: 4/CU, co-residency guaranteed
#define MAXSEGS 64

// ---------- tier-3 fallback kernels (R1/R6-proven) ----------
__global__ void zero_f4_kernel(float4* __restrict__ out, int n4) {
    int i = blockIdx.x * blockDim.x + threadIdx.x;
    if (i < n4) out[i] = make_float4(0.f, 0.f, 0.f, 0.f);
}

__global__ void scatter_atomic_kernel(const float* __restrict__ feat,
                                      const int* __restrict__ src,
                                      const int* __restrict__ dst,
                                      float* __restrict__ agg, int E) {
    int gid = blockIdx.x * blockDim.x + threadIdx.x;
    int e = gid >> 5;
    if (e >= E) return;
    int q = gid & 31;
    const float4 v = ((const float4*)(feat + (size_t)src[e] * F))[q];
    float* o = agg + (size_t)dst[e] * F + (q << 2);
    atomicAdd(o + 0, v.x);
    atomicAdd(o + 1, v.y);
    atomicAdd(o + 2, v.z);
    atomicAdd(o + 3, v.w);
}

__global__ __launch_bounds__(256) void linear_relu_w_kernel(
        float* __restrict__ h, const float* __restrict__ W,
        const float* __restrict__ b, int N) {
    __shared__ __align__(16) float sA[64][132];
    const int tid = threadIdx.x;
    const int row0 = blockIdx.x * 64;
    for (int i = tid; i < 64 * 32; i += 256) {
        int r = i >> 5, q = i & 31;
        int gr = row0 + r;
        float4 v = make_float4(0.f, 0.f, 0.f, 0.f);
        if (gr < N) v = ((const float4*)(h + (size_t)gr * F))[q];
        *((float4*)&sA[r][q << 2]) = v;
    }
    __syncthreads();
    const int tr = tid >> 5, tc = tid & 31;
    float acc[8][4];
#pragma unroll
    for (int i = 0; i < 8; ++i)
#pragma unroll
        for (int j = 0; j < 4; ++j) acc[i][j] = 0.f;
    const float* Wr0 = W + (size_t)(tc * 4 + 0) * F;
    const float* Wr1 = W + (size_t)(tc * 4 + 1) * F;
    const float* Wr2 = W + (size_t)(tc * 4 + 2) * F;
    const float* Wr3 = W + (size_t)(tc * 4 + 3) * F;
    for (int k = 0; k < F; k += 4) {
        const float4 w0 = *(const float4*)&Wr0[k];
        const float4 w1 = *(const float4*)&Wr1[k];
        const float4 w2 = *(const float4*)&Wr2[k];
        const float4 w3 = *(const float4*)&Wr3[k];
#pragma unroll
        for (int i = 0; i < 8; ++i) {
            const float4 a = *(const float4*)&sA[tr * 8 + i][k];
            acc[i][0] += a.x * w0.x + a.y * w0.y + a.z * w0.z + a.w * w0.w;
            acc[i][1] += a.x * w1.x + a.y * w1.y + a.z * w1.z + a.w * w1.w;
            acc[i][2] += a.x * w2.x + a.y * w2.y + a.z * w2.z + a.w * w2.w;
            acc[i][3] += a.x * w3.x + a.y * w3.y + a.z * w3.z + a.w * w3.w;
        }
    }
    const float4 bias = ((const float4*)b)[tc];
#pragma unroll
    for (int i = 0; i < 8; ++i) {
        int gr = row0 + tr * 8 + i;
        if (gr < N) {
            float4 o;
            o.x = fmaxf(acc[i][0] + bias.x, 0.f);
            o.y = fmaxf(acc[i][1] + bias.y, 0.f);
            o.z = fmaxf(acc[i][2] + bias.z, 0.f);
            o.w = fmaxf(acc[i][3] + bias.w, 0.f);
            ((float4*)(h + (size_t)gr * F))[tc] = o;
        }
    }
}

// ---------- 2-launch path ----------

// Launch 1: transpose W, zero counts, zero barrier/queue control words.
__global__ void init_kernel(const float* __restrict__ W, float* __restrict__ wT,
                            int* __restrict__ counts, int* __restrict__ ctrl, int N) {
    int i = blockIdx.x * 256 + threadIdx.x;
    if (i < F * F) { int o = i >> 7, k = i & 127; wT[k * F + o] = W[i]; }
    if (i < N) counts[i] = 0;
    if (i < 8) ctrl[i] = 0;
}

// Device-wide barrier: generation-counting, agent-scope. Requires all GRID
// blocks co-resident (guaranteed by __launch_bounds__(256,4) + 18KB LDS).
__device__ __forceinline__ void grid_barrier(int* bar, int* gen) {
    __syncthreads();   // emits s_waitcnt vmcnt(0): this block's stores are in L2
    if (threadIdx.x == 0) {
        __threadfence();  // agent-scope release: L2 writeback visible device-wide
        const int g = __hip_atomic_load(gen, __ATOMIC_RELAXED, __HIP_MEMORY_SCOPE_AGENT);
        const int arrived =
            __hip_atomic_fetch_add(bar, 1, __ATOMIC_ACQ_REL, __HIP_MEMORY_SCOPE_AGENT);
        if (arrived == GRID - 1) {
            __hip_atomic_store(bar, 0, __ATOMIC_RELAXED, __HIP_MEMORY_SCOPE_AGENT);
            __hip_atomic_fetch_add(gen, 1, __ATOMIC_RELEASE, __HIP_MEMORY_SCOPE_AGENT);
        } else {
            while (__hip_atomic_load(gen, __ATOMIC_ACQUIRE, __HIP_MEMORY_SCOPE_AGENT) == g)
                __builtin_amdgcn_s_sleep(2);
        }
        __threadfence();  // acquire side: invalidate stale L1/L2 lines
    }
    __syncthreads();
}

// Launch 2: hist -> seg-scan -> place -> fused agg+GEMM, one dispatch.
__global__ __launch_bounds__(256, 4) void mega_kernel(
        const float* __restrict__ feat, const int* __restrict__ src,
        const int* __restrict__ dst, const float* __restrict__ wT,
        const float* __restrict__ b, float* __restrict__ out,
        int* __restrict__ counts, int* __restrict__ offsL,
        int* __restrict__ tileSums, int* __restrict__ ctrl,
        int* __restrict__ ssrc, int N, int E, int NB, int ntiles) {
    __shared__ __align__(16) float sA[TN][132];
    __shared__ int tilePref[MAXSEGS];
    __shared__ int s_tile;
    int* bar = ctrl;
    int* gen = ctrl + 1;
    int* qtile = ctrl + 2;
    const int tid = threadIdx.x;
    const int gid0 = blockIdx.x * 256 + tid;
    const int gsz = GRID * 256;

    // P1: histogram of dst.
    for (int e = gid0; e < E; e += gsz) atomicAdd(&counts[dst[e]], 1);
    grid_barrier(bar, gen);

    // P2: per-segment (1024-node) exclusive scan; tileSums[seg] = segment total.
    if (blockIdx.x < NB) {
        int* lds = (int*)sA;
        const int i0 = blockIdx.x * SEG + tid * 4;
        int v[4];
        int s = 0;
#pragma unroll
        for (int j = 0; j < 4; ++j) {
            int i = i0 + j;
            v[j] = (i < N) ? counts[i] : 0;
            s += v[j];
        }
        lds[tid] = s;
        __syncthreads();
        for (int off = 1; off < 256; off <<= 1) {
            int t = (tid >= off) ? lds[tid - off] : 0;
            __syncthreads();
            lds[tid] += t;
            __syncthreads();
        }
        int excl = lds[tid] - s;
#pragma unroll
        for (int j = 0; j < 4; ++j) {
            int i = i0 + j;
            if (i < N) offsL[i] = excl;
            excl += v[j];
        }
        if (tid == 255) tileSums[blockIdx.x] = lds[255];
    }
    grid_barrier(bar, gen);

    // P3: each block computes segment prefixes locally (tiny), then places
    // edges: global pos = local atomic cursor + segment prefix.
    if (tid == 0) {
        int run = 0;
        for (int c = 0; c < NB; ++c) { tilePref[c] = run; run += tileSums[c]; }
    }
    __syncthreads();
    for (int e = gid0; e < E; e += gsz) {
        int d = dst[e];
        int pos = atomicAdd(&offsL[d], 1) + tilePref[d >> 10];
        ssrc[pos] = src[e];
    }
    grid_barrier(bar, gen);
    // Post-place: offsL[v] = local end; global segment = [end-counts[v], end).

    // P4: fused aggregate + linear + relu over dynamic tile queue.
    for (;;) {
        if (tid == 0) s_tile = atomicAdd(qtile, 1);
        __syncthreads();
        const int tile = s_tile;
        if (tile >= ntiles) break;
        const int row0 = tile * TN;
        const int wave = tid >> 6;
        const int lane = tid & 63;
        const int half = lane >> 5;
        const int q = lane & 31;
        const float4* feat4 = (const float4*)feat;

        for (int r = wave * 8; r < wave * 8 + 8; ++r) {
            const int v = row0 + r;
            float ax = 0.f, ay = 0.f, az = 0.f, aw = 0.f;
            if (v < N) {
                const int s1 = offsL[v] + tilePref[v >> 10];
                const int s0 = s1 - counts[v];
                int e = s0 + half;
                for (; e + 6 < s1; e += 8) {
                    int i0 = ssrc[e], i1 = ssrc[e + 2], i2 = ssrc[e + 4], i3 = ssrc[e + 6];
                    const float4 f0 = feat4[(size_t)i0 * 32 + q];
                    const float4 f1 = feat4[(size_t)i1 * 32 + q];
                    const float4 f2 = feat4[(size_t)i2 * 32 + q];
                    const float4 f3 = feat4[(size_t)i3 * 32 + q];
                    ax += (f0.x + f1.x) + (f2.x + f3.x);
                    ay += (f0.y + f1.y) + (f2.y + f3.y);
                    az += (f0.z + f1.z) + (f2.z + f3.z);
                    aw += (f0.w + f1.w) + (f2.w + f3.w);
                }
                for (; e < s1; e += 2) {
                    const float4 f0 = feat4[(size_t)ssrc[e] * 32 + q];
                    ax += f0.x; ay += f0.y; az += f0.z; aw += f0.w;
                }
            }
            ax += __shfl_xor(ax, 32);
            ay += __shfl_xor(ay, 32);
            az += __shfl_xor(az, 32);
            aw += __shfl_xor(aw, 32);
            if (half == 0) {
                float4 r4; r4.x = ax; r4.y = ay; r4.z = az; r4.w = aw;
                *(float4*)&sA[r][q << 2] = r4;
            }
        }
        __syncthreads();

        const int tr = tid >> 5;
        const int tc = tid & 31;
        float acc[4][4];
#pragma unroll
        for (int i = 0; i < 4; ++i)
#pragma unroll
            for (int j = 0; j < 4; ++j) acc[i][j] = 0.f;
        const float4* wT4 = (const float4*)wT;
        for (int k = 0; k < F; k += 4) {
            const float4 w0 = wT4[(k + 0) * 32 + tc];
            const float4 w1 = wT4[(k + 1) * 32 + tc];
            const float4 w2 = wT4[(k + 2) * 32 + tc];
            const float4 w3 = wT4[(k + 3) * 32 + tc];
#pragma unroll
            for (int i = 0; i < 4; ++i) {
                const float4 a = *(const float4*)&sA[tr * 4 + i][k];
                acc[i][0] += a.x * w0.x + a.y * w1.x + a.z * w2.x + a.w * w3.x;
                acc[i][1] += a.x * w0.y + a.y * w1.y + a.z * w2.y + a.w * w3.y;
                acc[i][2] += a.x * w0.z + a.y * w1.z + a.z * w2.z + a.w * w3.z;
                acc[i][3] += a.x * w0.w + a.y * w1.w + a.z * w2.w + a.w * w3.w;
            }
        }
        const float4 bias = ((const float4*)b)[tc];
#pragma unroll
        for (int i = 0; i < 4; ++i) {
            int gr = row0 + tr * 4 + i;
            if (gr < N) {
                float4 o;
                o.x = fmaxf(acc[i][0] + bias.x, 0.f);
                o.y = fmaxf(acc[i][1] + bias.y, 0.f);
                o.z = fmaxf(acc[i][2] + bias.z, 0.f);
                o.w = fmaxf(acc[i][3] + bias.w, 0.f);
                ((float4*)(out + (size_t)gr * F))[tc] = o;
            }
        }
        __syncthreads();   // protect sA and s_tile for next iteration
    }
}

extern "C" void kernel_launch(void* const* d_in, const int* in_sizes, int n_in,
                              void* d_out, int out_size, void* d_ws, size_t ws_size,
                              hipStream_t stream) {
    const float* feat = (const float*)d_in[0];
    const int*   src  = (const int*)d_in[1];
    const int*   dst  = (const int*)d_in[2];
    const float* W    = (const float*)d_in[3];
    const float* b    = (const float*)d_in[4];
    float* out = (float*)d_out;

    const int N = in_sizes[0] / F;   // 50000
    const int E = in_sizes[1];       // 800000
    const int NB = (N + SEG - 1) / SEG;          // 49
    const int ntiles = (N + TN - 1) / TN;        // 1563

    // ws layout (4B): counts[N] | offsL[N] | tileSums[64] | ctrl[8] | ssrc[E] | pad | wT[F*F]
    const size_t ints_before = (size_t)N + N + 64 + 8 + E;
    const size_t wT_off = (ints_before + 3) & ~(size_t)3;
    const size_t ws_needed = (wT_off + (size_t)F * F) * sizeof(int);

    if (ws_size >= ws_needed && NB <= MAXSEGS) {
        int* counts   = (int*)d_ws;
        int* offsL    = counts + N;
        int* tileSums = offsL + N;
        int* ctrl     = tileSums + 64;
        int* ssrc     = ctrl + 8;
        float* wT     = (float*)d_ws + wT_off;

        init_kernel<<<(N + 255) / 256, 256, 0, stream>>>(W, wT, counts, ctrl, N);
        mega_kernel<<<GRID, 256, 0, stream>>>(feat, src, dst, wT, b, out,
                                              counts, offsL, tileSums, ctrl, ssrc,
                                              N, E, NB, ntiles);
    } else {
        const int n4 = N * (F / 4);
        zero_f4_kernel<<<(n4 + 255) / 256, 256, 0, stream>>>((float4*)out, n4);
        const int sthreads = E * 32;
        scatter_atomic_kernel<<<(sthreads + 255) / 256, 256, 0, stream>>>(feat, src, dst, out, E);
        linear_relu_w_kernel<<<(N + 63) / 64, 256, 0, stream>>>(out, W, b, N);
    }
}